// Round 3
// baseline (550.770 us; speedup 1.0000x reference)
//
#include <hip/hip_runtime.h>
#include <math.h>

#define Bb 128
#define Hh 4
#define Nn 8192
#define Dd 64

constexpr float BETA = 10.0f;
constexpr float EPSV = 1e-8f;

typedef float f32x4 __attribute__((ext_vector_type(4)));  // for nontemporal ops

// d_out layout (flat float32, reference return order):
constexpr long long OFF_RC = 0;                              // read_combined (B,D)
constexpr long long OFF_RW = (long long)Bb * Dd;             // r_w (B,H,N)
constexpr long long OFF_NM = OFF_RW + (long long)Bb*Hh*Nn;   // new_memory (B,N,D)
constexpr long long OFF_WW = OFF_NM + (long long)Bb*Nn*Dd;   // w_w (B,H,N)

// workspace layout:
//   cand_v : float[1024*256]            (per (b,head8,chunk) top-8 values)
//   cand_i : int  [1024*256]            (matching global n indices)

// ---------------------------------------------------------------------------
// K1: stream memory once. Per row: norm + 8 key dots (4 read + 4 write heads).
// Writes new_memory = 4*memory, zeros the r_w/w_w output rows for this chunk,
// and reduces its 256 sims per head to a per-chunk top-8 candidate list
// (hierarchical top-k: the global top-8 is always contained in the union of
// per-chunk top-8s, tie-break by lower index preserved at both levels).
// Load loop is software-pipelined: next row-chunk's float4 issues before the
// shuffle-reduce chain of the current one.
// ---------------------------------------------------------------------------
__global__ __launch_bounds__(256) void k1_sims(
    const float* __restrict__ mem, const float* __restrict__ rkeys,
    const float* __restrict__ wkeys, float* __restrict__ out,
    float* __restrict__ cand_v, int* __restrict__ cand_i)
{
  __shared__ __align__(16) float keys[8 * 64];   // heads 0-3 read, 4-7 write
  __shared__ float knorm[8];
  __shared__ __align__(16) float sims[8][256];
  const int b = blockIdx.x >> 5;     // 32 chunks per batch
  const int c = blockIdx.x & 31;
  const int t = threadIdx.x;

  keys[t]       = rkeys[b * 256 + t];
  keys[256 + t] = wkeys[b * 256 + t];
  __syncthreads();
  if (t < 8) {
    float s = 0.f;
    for (int d = 0; d < 64; ++d) { float k = keys[t * 64 + d]; s += k * k; }
    knorm[t] = fmaxf(sqrtf(s), EPSV);
  }
  __syncthreads();

  const int g = t >> 4, q = t & 15;          // group (row), lane-in-group
  const float4* kvec = (const float4*)keys;  // kvec[h*16 + q]
  const int base = c * 256;

  // hoisted pointers: per-it stride = 16 rows * 64 floats = 256 f32x4
  const long long rowoff0 = ((long long)b * Nn + base + g) * Dd;
  const f32x4* mp = ((const f32x4*)(mem + rowoff0)) + q;
  f32x4*       op = ((f32x4*)(out + OFF_NM + rowoff0)) + q;

  f32x4 v = __builtin_nontemporal_load(mp);
  for (int it = 0; it < 16; ++it) {
    f32x4 vn;
    if (it < 15) vn = __builtin_nontemporal_load(mp + (it + 1) * 256);
    float acc[9];
    acc[8] = v.x*v.x + v.y*v.y + v.z*v.z + v.w*v.w;   // norm^2 partial
#pragma unroll
    for (int h = 0; h < 8; ++h) {
      float4 k4 = kvec[h * 16 + q];
      acc[h] = v.x*k4.x + v.y*k4.y + v.z*k4.z + v.w*k4.w;
    }
#pragma unroll
    for (int off = 1; off < 16; off <<= 1) {
#pragma unroll
      for (int j = 0; j < 9; ++j) acc[j] += __shfl_xor(acc[j], off, 64);
    }
    // new_memory = 4 * memory (bulk case; K23 fixes the <=32 written rows)
    f32x4 nm;
    nm.x = 4.f*v.x; nm.y = 4.f*v.y; nm.z = 4.f*v.z; nm.w = 4.f*v.w;
    __builtin_nontemporal_store(nm, op + it * 256);
    if (q < 8) {
      float m_norm = fmaxf(sqrtf(acc[8]), EPSV);
      sims[q][it * 16 + g] = BETA * acc[q] / (knorm[q] * m_norm + EPSV);
    }
    v = vn;
  }

  // zero this chunk's segment of all 8 output weight rows (K23 scatters later)
  {
    const int zh = t >> 5, zq = t & 31;       // 8 heads x 32 lanes x 2 f32x4
    long long zo = (zh < 4) ? (OFF_RW + (long long)(b*4+zh) * Nn)
                            : (OFF_WW + (long long)(b*4+zh-4) * Nn);
    f32x4 z = {0.f, 0.f, 0.f, 0.f};
    f32x4* zp = (f32x4*)(out + zo + base);
    __builtin_nontemporal_store(z, zp + zq);
    __builtin_nontemporal_store(z, zp + zq + 32);
  }
  __syncthreads();

  // per-chunk top-8 per head: wave w handles heads 2w, 2w+1, no barriers.
  const int wid = t >> 6, lane = t & 63;
#pragma unroll
  for (int hh = 0; hh < 2; ++hh) {
    const int h = wid * 2 + hh;
    float4 sv = ((const float4*)(&sims[h][0]))[lane];  // sims[h][lane*4+j]
    float v0 = sv.x, v1 = sv.y, v2 = sv.z, v3 = sv.w;
    const int nb = base + lane * 4;
    const long long cofs = ((long long)(b * 8 + h) * 32 + c) * 8;
#pragma unroll
    for (int k = 0; k < 8; ++k) {
      // local best of 4 (strict > keeps lowest index on ties: idx grows with j)
      float bv = v0; int bj = 0;
      if (v1 > bv) { bv = v1; bj = 1; }
      if (v2 > bv) { bv = v2; bj = 2; }
      if (v3 > bv) { bv = v3; bj = 3; }
      int bi = nb + bj;
#pragma unroll
      for (int off = 1; off < 64; off <<= 1) {
        float ov = __shfl_xor(bv, off, 64);
        int   oi = __shfl_xor(bi, off, 64);
        if (ov > bv || (ov == bv && oi < bi)) { bv = ov; bi = oi; }
      }
      if (lane == k) { cand_v[cofs + k] = bv; cand_i[cofs + k] = bi; }
      // invalidate the extracted slot (owner lane only; others no-op)
      int r = bi - nb;
      if (r == 0) v0 = -3.0e38f;
      else if (r == 1) v1 = -3.0e38f;
      else if (r == 2) v2 = -3.0e38f;
      else if (r == 3) v3 = -3.0e38f;
    }
  }
}

// ---------------------------------------------------------------------------
// K23: fused merge + apply. One block per batch b (256 threads = 4 waves).
// Phase A (merge): wave w reduces rows h8=2w,2w+1 (32 chunks x 8 candidates,
//   L2-resident) to the global top-8, softmax, scatters weights into the
//   pre-zeroed output row; results kept in LDS.
// Phase B: read_combined — wave w accumulates read head w's 8 entries.
// Phase C: write rows — wave w owns entries e === w (mod 4); first-occurrence
//   owner merges duplicates (owners have distinct n -> parallel-safe).
// ---------------------------------------------------------------------------
__global__ __launch_bounds__(256) void k23_merge_apply(
    const float* __restrict__ mem, const float* __restrict__ wvals,
    const float* __restrict__ erase, const float* __restrict__ cand_v,
    const int* __restrict__ cand_i, float* __restrict__ out)
{
  const int b = blockIdx.x;
  const int t = threadIdx.x;
  const int w = t >> 6, lane = t & 63;
  __shared__ int   sidx[8][8];     // [h8][k] global n indices of top-8
  __shared__ float swtv[8][8];     // [h8][k] softmax weights
  __shared__ float part[4][64];

  // ---- Phase A: merge 2 rows per wave ----
#pragma unroll
  for (int hh = 0; hh < 2; ++hh) {
    const int h8 = w * 2 + hh;
    const long long cbase = ((long long)(b * 8 + h8)) * 256;
    float4 cv4 = ((const float4*)(cand_v + cbase))[lane];
    int4   ci4 = ((const int4*)(cand_i + cbase))[lane];
    float v0 = cv4.x, v1 = cv4.y, v2 = cv4.z, v3 = cv4.w;
    int   i0 = ci4.x, i1 = ci4.y, i2 = ci4.z, i3 = ci4.w;

    float cv[8]; int ci[8];        // static-indexed only (unrolled)
#pragma unroll
    for (int k = 0; k < 8; ++k) {
      float bv = v0; int bi = i0;
      if (v1 > bv || (v1 == bv && i1 < bi)) { bv = v1; bi = i1; }
      if (v2 > bv || (v2 == bv && i2 < bi)) { bv = v2; bi = i2; }
      if (v3 > bv || (v3 == bv && i3 < bi)) { bv = v3; bi = i3; }
#pragma unroll
      for (int off = 1; off < 64; off <<= 1) {
        float ov = __shfl_xor(bv, off, 64);
        int   oi = __shfl_xor(bi, off, 64);
        if (ov > bv || (ov == bv && oi < bi)) { bv = ov; bi = oi; }
      }
      cv[k] = bv; ci[k] = bi;
      // invalidate by index (indices are globally unique across candidates)
      if (i0 == bi) v0 = -3.0e38f;
      if (i1 == bi) v1 = -3.0e38f;
      if (i2 == bi) v2 = -3.0e38f;
      if (i3 == bi) v3 = -3.0e38f;
    }

    // softmax over the 8 selected (others are exactly 0 in fp32, same as ref)
    float m = cv[0], den = 0.f, ex[8];
#pragma unroll
    for (int k = 0; k < 8; ++k) { ex[k] = expf(cv[k] - m); den += ex[k]; }

    float* row = out + ((h8 < 4) ? (OFF_RW + (long long)(b*4+h8) * Nn)
                                 : (OFF_WW + (long long)(b*4+h8-4) * Nn));
#pragma unroll
    for (int k = 0; k < 8; ++k) {
      if (lane == k) {
        float wg = ex[k] / den;
        row[ci[k]]  = wg;
        sidx[h8][k] = ci[k];
        swtv[h8][k] = wg;
      }
    }
  }
  __syncthreads();

  // ---- Phase B: read_combined (wave w handles read head w) ----
  float acc = 0.f;
#pragma unroll
  for (int e8 = 0; e8 < 8; ++e8) {
    const int n  = sidx[w][e8];
    const float wt = swtv[w][e8];
    acc += wt * mem[((long long)b * Nn + n) * Dd + lane];
  }
  part[w][lane] = acc;
  __syncthreads();
  if (w == 0)
    out[OFF_RC + b*64 + lane] =
        0.25f * (part[0][lane] + part[1][lane] + part[2][lane] + part[3][lane]);

  // ---- Phase C: write rows (entries e = ee*4 + w, wave-uniform) ----
  for (int ee = 0; ee < 8; ++ee) {
    const int e = ee * 4 + w;
    const int n = sidx[4 + (e >> 3)][e & 7];
    bool first = true;
    for (int j = 0; j < e; ++j)
      if (sidx[4 + (j >> 3)][j & 7] == n) first = false;
    if (first) {                             // uniform within the wave
      float E = 0.f, A = 0.f;
      for (int j = e; j < 32; ++j)
        if (sidx[4 + (j >> 3)][j & 7] == n) {
          const int h = j >> 3;
          const float wj = swtv[4 + (j >> 3)][j & 7];
          E += wj * erase[((long long)b*4 + h) * 64 + lane];
          A += wj * wvals[((long long)b*4 + h) * 64 + lane];
        }
      const float m = mem[((long long)b * Nn + n) * Dd + lane];
      out[OFF_NM + ((long long)b * Nn + n) * Dd + lane] = m * (4.f - E) + A;
    }
  }
}

extern "C" void kernel_launch(void* const* d_in, const int* in_sizes, int n_in,
                              void* d_out, int out_size, void* d_ws, size_t ws_size,
                              hipStream_t stream) {
  (void)in_sizes; (void)n_in; (void)out_size; (void)ws_size;
  const float* mem   = (const float*)d_in[0];
  const float* rkeys = (const float*)d_in[1];
  const float* wkeys = (const float*)d_in[2];
  const float* wvals = (const float*)d_in[3];
  const float* erase = (const float*)d_in[4];
  float* out = (float*)d_out;
  float* cand_v = (float*)d_ws;
  int*   cand_i = (int*)((char*)d_ws + (long long)1024*256*sizeof(float));

  hipLaunchKernelGGL(k1_sims, dim3(Bb * 32), dim3(256), 0, stream,
                     mem, rkeys, wkeys, out, cand_v, cand_i);
  hipLaunchKernelGGL(k23_merge_apply, dim3(Bb), dim3(256), 0, stream,
                     mem, wvals, erase, cand_v, cand_i, out);
}

// Round 4
// 510.130 us; speedup vs baseline: 1.0797x; 1.0797x over previous
//
#include <hip/hip_runtime.h>
#include <math.h>

#define Bb 128
#define Hh 4
#define Nn 8192
#define Dd 64

constexpr float BETA = 10.0f;
constexpr float EPSV = 1e-8f;

typedef float f32x4 __attribute__((ext_vector_type(4)));  // for nontemporal ops

// d_out layout (flat float32, reference return order):
constexpr long long OFF_RC = 0;                              // read_combined (B,D)
constexpr long long OFF_RW = (long long)Bb * Dd;             // r_w (B,H,N)
constexpr long long OFF_NM = OFF_RW + (long long)Bb*Hh*Nn;   // new_memory (B,N,D)
constexpr long long OFF_WW = OFF_NM + (long long)Bb*Nn*Dd;   // w_w (B,H,N)

// workspace layout:
//   cand_v : float[1024*256]            (per (b,head8,chunk) top-8 values)
//   cand_i : int  [1024*256]            (matching global n indices)

// ---------------------------------------------------------------------------
// K1: stream memory once. Per row: norm + 8 key dots (4 read + 4 write heads).
// Writes new_memory = 4*memory, zeros the r_w/w_w output rows for this chunk,
// and reduces its 256 sims per head to a per-chunk top-8 candidate list.
//
// DS-pipe diet (this round): the 9-accumulator 16-lane reduce uses a
// value-split butterfly (12 shfl/iter, was 36): each stage exchanges only the
// accumulators the partner half keeps. Final layout: even lane q holds the
// full dot for head q>>1 (j = 4*b3 + 2*b2 + b1). Top-8 uses a value-only
// 6-shfl max + ballot/ffs owner election (was 12 shfl with carried index);
// lowest set lane == lowest global index, so jax.lax.top_k tie-break holds.
// ---------------------------------------------------------------------------
__global__ __launch_bounds__(256) void k1_sims(
    const float* __restrict__ mem, const float* __restrict__ rkeys,
    const float* __restrict__ wkeys, float* __restrict__ out,
    float* __restrict__ cand_v, int* __restrict__ cand_i)
{
  __shared__ __align__(16) float keys[8 * 64];   // heads 0-3 read, 4-7 write
  __shared__ float knorm[8];
  __shared__ __align__(16) float sims[8][260];   // +4 pad: conflict-free head writes
  const int b = blockIdx.x >> 5;     // 32 chunks per batch
  const int c = blockIdx.x & 31;
  const int t = threadIdx.x;

  keys[t]       = rkeys[b * 256 + t];
  keys[256 + t] = wkeys[b * 256 + t];
  __syncthreads();
  if (t < 8) {
    float s = 0.f;
    for (int d = 0; d < 64; ++d) { float k = keys[t * 64 + d]; s += k * k; }
    knorm[t] = fmaxf(sqrtf(s), EPSV);
  }
  __syncthreads();

  const int g = t >> 4, q = t & 15;          // group (row), lane-in-group
  const float4* kvec = (const float4*)keys;  // kvec[h*16 + q]
  const int base = c * 256;
  const bool hi8 = (q & 8) != 0, hi4 = (q & 4) != 0, hi2 = (q & 2) != 0;
  const int hsel = q >> 1;                   // head owned by even lanes

  // hoisted pointers: per-it stride = 16 rows * 64 floats = 256 f32x4
  const long long rowoff0 = ((long long)b * Nn + base + g) * Dd;
  const f32x4* mp = ((const f32x4*)(mem + rowoff0)) + q;
  f32x4*       op = ((f32x4*)(out + OFF_NM + rowoff0)) + q;

  f32x4 v = __builtin_nontemporal_load(mp);
  for (int it = 0; it < 16; ++it) {
    f32x4 vn;
    if (it < 15) vn = __builtin_nontemporal_load(mp + (it + 1) * 256);
    float acc[9];
    acc[8] = v.x*v.x + v.y*v.y + v.z*v.z + v.w*v.w;   // norm^2 partial
#pragma unroll
    for (int h = 0; h < 8; ++h) {
      float4 k4 = kvec[h * 16 + q];
      acc[h] = v.x*k4.x + v.y*k4.y + v.z*k4.z + v.w*k4.w;
    }
    // value-split butterfly reduce over the 16-lane group (8 dots in 8 shfl)
    float r4[4];
#pragma unroll
    for (int j = 0; j < 4; ++j) {
      float snd = hi8 ? acc[j]     : acc[j + 4];   // what partner keeps
      float kp  = hi8 ? acc[j + 4] : acc[j];       // what I keep
      r4[j] = kp + __shfl_xor(snd, 8, 64);
    }
    float r2[2];
#pragma unroll
    for (int j = 0; j < 2; ++j) {
      float snd = hi4 ? r4[j]     : r4[j + 2];
      float kp  = hi4 ? r4[j + 2] : r4[j];
      r2[j] = kp + __shfl_xor(snd, 4, 64);
    }
    {
      float snd = hi2 ? r2[0] : r2[1];
      float kp  = hi2 ? r2[1] : r2[0];
      r2[0] = kp + __shfl_xor(snd, 2, 64);
    }
    float x = r2[0] + __shfl_xor(r2[0], 1, 64);
    // norm: plain 4-stage butterfly
    float nrm = acc[8];
    nrm += __shfl_xor(nrm, 1, 64);
    nrm += __shfl_xor(nrm, 2, 64);
    nrm += __shfl_xor(nrm, 4, 64);
    nrm += __shfl_xor(nrm, 8, 64);

    // new_memory = 4 * memory (bulk case; K23 fixes the <=32 written rows)
    f32x4 nm;
    nm.x = 4.f*v.x; nm.y = 4.f*v.y; nm.z = 4.f*v.z; nm.w = 4.f*v.w;
    __builtin_nontemporal_store(nm, op + it * 256);
    if (!(q & 1)) {
      float m_norm = fmaxf(sqrtf(nrm), EPSV);
      sims[hsel][it * 16 + g] = BETA * x / (knorm[hsel] * m_norm + EPSV);
    }
    v = vn;
  }

  // zero this chunk's segment of all 8 output weight rows (K23 scatters later)
  {
    const int zh = t >> 5, zq = t & 31;       // 8 heads x 32 lanes x 2 f32x4
    long long zo = (zh < 4) ? (OFF_RW + (long long)(b*4+zh) * Nn)
                            : (OFF_WW + (long long)(b*4+zh-4) * Nn);
    f32x4 z = {0.f, 0.f, 0.f, 0.f};
    f32x4* zp = (f32x4*)(out + zo + base);
    __builtin_nontemporal_store(z, zp + zq);
    __builtin_nontemporal_store(z, zp + zq + 32);
  }
  __syncthreads();

  // per-chunk top-8 per head: wave w handles heads 2w, 2w+1, no barriers.
  const int wid = t >> 6, lane = t & 63;
#pragma unroll
  for (int hh = 0; hh < 2; ++hh) {
    const int h = wid * 2 + hh;
    const float4* sp = (const float4*)(&sims[h][0]);
    float4 sv = sp[lane];                    // sims[h][lane*4 + j]
    float v0 = sv.x, v1 = sv.y, v2 = sv.z, v3 = sv.w;
    const int nb = base + lane * 4;
    const long long cofs = ((long long)(b * 8 + h) * 32 + c) * 8;
#pragma unroll
    for (int k = 0; k < 8; ++k) {
      // local best of 4 (strict > keeps lowest index on ties: idx grows with j)
      float bv = v0; int bj = 0;
      if (v1 > bv) { bv = v1; bj = 1; }
      if (v2 > bv) { bv = v2; bj = 2; }
      if (v3 > bv) { bv = v3; bj = 3; }
      // value-only wave max (6 shfl), then elect lowest lane holding it.
      float gm = bv;
#pragma unroll
      for (int off = 1; off < 64; off <<= 1) gm = fmaxf(gm, __shfl_xor(gm, off, 64));
      unsigned long long mk = __ballot(bv == gm);
      int src = __ffsll((long long)mk) - 1;  // lowest lane == lowest global idx
      if (lane == src) {
        cand_v[cofs + k] = gm;
        cand_i[cofs + k] = nb + bj;
        if      (bj == 0) v0 = -3.0e38f;
        else if (bj == 1) v1 = -3.0e38f;
        else if (bj == 2) v2 = -3.0e38f;
        else              v3 = -3.0e38f;
      }
    }
  }
}

// ---------------------------------------------------------------------------
// K23: fused merge + apply. One block per batch b (256 threads = 4 waves).
// Phase A (merge): wave w reduces rows h8=2w,2w+1 (32 chunks x 8 candidates,
//   L2-resident) to the global top-8, softmax, scatters weights into the
//   pre-zeroed output row; results kept in LDS.
// Phase B: read_combined — wave w accumulates read head w's 8 entries.
// Phase C: write rows — wave w owns entries e === w (mod 4); first-occurrence
//   owner merges duplicates (owners have distinct n -> parallel-safe).
// ---------------------------------------------------------------------------
__global__ __launch_bounds__(256) void k23_merge_apply(
    const float* __restrict__ mem, const float* __restrict__ wvals,
    const float* __restrict__ erase, const float* __restrict__ cand_v,
    const int* __restrict__ cand_i, float* __restrict__ out)
{
  const int b = blockIdx.x;
  const int t = threadIdx.x;
  const int w = t >> 6, lane = t & 63;
  __shared__ int   sidx[8][8];     // [h8][k] global n indices of top-8
  __shared__ float swtv[8][8];     // [h8][k] softmax weights
  __shared__ float part[4][64];

  // ---- Phase A: merge 2 rows per wave ----
#pragma unroll
  for (int hh = 0; hh < 2; ++hh) {
    const int h8 = w * 2 + hh;
    const long long cbase = ((long long)(b * 8 + h8)) * 256;
    float4 cv4 = ((const float4*)(cand_v + cbase))[lane];
    int4   ci4 = ((const int4*)(cand_i + cbase))[lane];
    float v0 = cv4.x, v1 = cv4.y, v2 = cv4.z, v3 = cv4.w;
    int   i0 = ci4.x, i1 = ci4.y, i2 = ci4.z, i3 = ci4.w;

    float cv[8]; int ci[8];        // static-indexed only (unrolled)
#pragma unroll
    for (int k = 0; k < 8; ++k) {
      float bv = v0; int bi = i0;
      if (v1 > bv || (v1 == bv && i1 < bi)) { bv = v1; bi = i1; }
      if (v2 > bv || (v2 == bv && i2 < bi)) { bv = v2; bi = i2; }
      if (v3 > bv || (v3 == bv && i3 < bi)) { bv = v3; bi = i3; }
#pragma unroll
      for (int off = 1; off < 64; off <<= 1) {
        float ov = __shfl_xor(bv, off, 64);
        int   oi = __shfl_xor(bi, off, 64);
        if (ov > bv || (ov == bv && oi < bi)) { bv = ov; bi = oi; }
      }
      cv[k] = bv; ci[k] = bi;
      // invalidate by index (indices are globally unique across candidates)
      if (i0 == bi) v0 = -3.0e38f;
      if (i1 == bi) v1 = -3.0e38f;
      if (i2 == bi) v2 = -3.0e38f;
      if (i3 == bi) v3 = -3.0e38f;
    }

    // softmax over the 8 selected (others are exactly 0 in fp32, same as ref)
    float m = cv[0], den = 0.f, ex[8];
#pragma unroll
    for (int k = 0; k < 8; ++k) { ex[k] = expf(cv[k] - m); den += ex[k]; }

    float* row = out + ((h8 < 4) ? (OFF_RW + (long long)(b*4+h8) * Nn)
                                 : (OFF_WW + (long long)(b*4+h8-4) * Nn));
#pragma unroll
    for (int k = 0; k < 8; ++k) {
      if (lane == k) {
        float wg = ex[k] / den;
        row[ci[k]]  = wg;
        sidx[h8][k] = ci[k];
        swtv[h8][k] = wg;
      }
    }
  }
  __syncthreads();

  // ---- Phase B: read_combined (wave w handles read head w) ----
  float acc = 0.f;
#pragma unroll
  for (int e8 = 0; e8 < 8; ++e8) {
    const int n  = sidx[w][e8];
    const float wt = swtv[w][e8];
    acc += wt * mem[((long long)b * Nn + n) * Dd + lane];
  }
  part[w][lane] = acc;
  __syncthreads();
  if (w == 0)
    out[OFF_RC + b*64 + lane] =
        0.25f * (part[0][lane] + part[1][lane] + part[2][lane] + part[3][lane]);

  // ---- Phase C: write rows (entries e = ee*4 + w, wave-uniform) ----
  for (int ee = 0; ee < 8; ++ee) {
    const int e = ee * 4 + w;
    const int n = sidx[4 + (e >> 3)][e & 7];
    bool first = true;
    for (int j = 0; j < e; ++j)
      if (sidx[4 + (j >> 3)][j & 7] == n) first = false;
    if (first) {                             // uniform within the wave
      float E = 0.f, A = 0.f;
      for (int j = e; j < 32; ++j)
        if (sidx[4 + (j >> 3)][j & 7] == n) {
          const int h = j >> 3;
          const float wj = swtv[4 + (j >> 3)][j & 7];
          E += wj * erase[((long long)b*4 + h) * 64 + lane];
          A += wj * wvals[((long long)b*4 + h) * 64 + lane];
        }
      const float m = mem[((long long)b * Nn + n) * Dd + lane];
      out[OFF_NM + ((long long)b * Nn + n) * Dd + lane] = m * (4.f - E) + A;
    }
  }
}

extern "C" void kernel_launch(void* const* d_in, const int* in_sizes, int n_in,
                              void* d_out, int out_size, void* d_ws, size_t ws_size,
                              hipStream_t stream) {
  (void)in_sizes; (void)n_in; (void)out_size; (void)ws_size;
  const float* mem   = (const float*)d_in[0];
  const float* rkeys = (const float*)d_in[1];
  const float* wkeys = (const float*)d_in[2];
  const float* wvals = (const float*)d_in[3];
  const float* erase = (const float*)d_in[4];
  float* out = (float*)d_out;
  float* cand_v = (float*)d_ws;
  int*   cand_i = (int*)((char*)d_ws + (long long)1024*256*sizeof(float));

  hipLaunchKernelGGL(k1_sims, dim3(Bb * 32), dim3(256), 0, stream,
                     mem, rkeys, wkeys, out, cand_v, cand_i);
  hipLaunchKernelGGL(k23_merge_apply, dim3(Bb), dim3(256), 0, stream,
                     mem, wvals, erase, cand_v, cand_i, out);
}